// Round 1
// baseline (897.974 us; speedup 1.0000x reference)
//
#include <hip/hip_runtime.h>

// Problem constants (B=4, S=2048, H=1024, E=8, F=4096, K=2)
#define T_TOKENS 8192
#define H_DIM 1024
#define E_EXP 8
#define F_DIM 4096
#define CAP 8192      // slot capacity per expert in tok/wt arrays
#define MT256 16      // 256-row m-tiles per expert (covers 4096 rows, 48 sigma)

typedef __attribute__((ext_vector_type(8))) short short8;
typedef __attribute__((ext_vector_type(8))) unsigned short ushort8;
typedef __attribute__((ext_vector_type(4))) float f32x4;

__device__ __forceinline__ unsigned short f2bf(float f) {
    unsigned int u = __float_as_uint(f);
    u += 0x7fffu + ((u >> 16) & 1u);   // round-to-nearest-even
    return (unsigned short)(u >> 16);
}

__device__ __forceinline__ float gelu_tanh(float x) {
    // jax.nn.gelu default (approximate=True)
    float z = 0.7978845608028654f * (x + 0.044715f * x * x * x);
    float t = 1.0f - 2.0f / (__expf(2.0f * z) + 1.0f);   // tanh(z)
    return 0.5f * x * (1.0f + t);
}

// async 16B global->LDS DMA (lane i of the wave lands at wave-uniform base + i*16)
__device__ __forceinline__ void gld16(const void* g, void* l) {
    __builtin_amdgcn_global_load_lds(
        (const __attribute__((address_space(1))) unsigned int*)g,
        (__attribute__((address_space(3))) unsigned int*)l,
        16, 0, 0);
}

// ---------------- router: top-2 + softmax; block-aggregated slot assignment --------
__global__ void router_kernel(const float* __restrict__ logits,
                              int* __restrict__ cnt,
                              int* __restrict__ tok,
                              float* __restrict__ wt) {
    __shared__ int hcnt[E_EXP];
    __shared__ int hbase[E_EXP];
    int tid = threadIdx.x;
    if (tid < E_EXP) hcnt[tid] = 0;
    __syncthreads();
    int t = blockIdx.x * 256 + tid;
    float l[E_EXP];
#pragma unroll
    for (int i = 0; i < E_EXP; i++) l[i] = logits[t * E_EXP + i];
    int i0 = 0; float s0 = l[0];
#pragma unroll
    for (int i = 1; i < E_EXP; i++) if (l[i] > s0) { s0 = l[i]; i0 = i; }
    int i1 = (i0 == 0) ? 1 : 0; float s1 = l[i1];
#pragma unroll
    for (int i = 0; i < E_EXP; i++) if (i != i0 && l[i] > s1) { s1 = l[i]; i1 = i; }
    float p0 = 1.0f / (1.0f + __expf(s1 - s0));
    float p1 = 1.0f - p0;
    int lo0 = atomicAdd(&hcnt[i0], 1);   // LDS atomic (fast, 8 addrs)
    int lo1 = atomicAdd(&hcnt[i1], 1);
    __syncthreads();
    if (tid < E_EXP) hbase[tid] = atomicAdd(&cnt[tid], hcnt[tid]);  // 8 global atomics/block
    __syncthreads();
    int sl0 = hbase[i0] + lo0;
    tok[i0 * CAP + sl0] = t; wt[i0 * CAP + sl0] = p0;
    int sl1 = hbase[i1] + lo1;
    tok[i1 * CAP + sl1] = t; wt[i1 * CAP + sl1] = p1;
}

__global__ void base_kernel(const int* __restrict__ cnt, int* __restrict__ base) {
    if (threadIdx.x == 0) {
        int b = 0;
        for (int e = 0; e < E_EXP; e++) { base[e] = b; b += cnt[e]; }
    }
}

// ---------------- x fp32 -> bf16 ----------------
__global__ void cvtx_kernel(const float* __restrict__ x, unsigned short* __restrict__ xg) {
    int i = blockIdx.x * 256 + threadIdx.x;   // over T*H/4
    float4 v = ((const float4*)x)[i];
    ushort4 o;
    o.x = f2bf(v.x); o.y = f2bf(v.y); o.z = f2bf(v.z); o.w = f2bf(v.w);
    ((ushort4*)xg)[i] = o;
}

// ---------------- transpose + convert: in [M,N] fp32 -> out [N,M] bf16 (per expert z)
__global__ void tcvt_kernel(const float* __restrict__ in, unsigned short* __restrict__ out,
                            int M, int N) {
    __shared__ float t[64][65];
    size_t eoff = (size_t)blockIdx.z * M * N;
    in += eoff; out += eoff;
    int r0 = blockIdx.x * 64, c0 = blockIdx.y * 64;
    int tid = threadIdx.x;
    int srow = tid >> 4;            // 0..15
    int scol = (tid & 15) * 4;
#pragma unroll
    for (int p = 0; p < 4; p++) {
        int row = p * 16 + srow;
        float4 v = *(const float4*)&in[(size_t)(r0 + row) * N + c0 + scol];
        t[row][scol + 0] = v.x; t[row][scol + 1] = v.y;
        t[row][scol + 2] = v.z; t[row][scol + 3] = v.w;
    }
    __syncthreads();
    int orow = tid >> 3;            // 0..31
    int ocb = (tid & 7) * 8;        // out col base (in-row index)
#pragma unroll
    for (int p = 0; p < 2; p++) {
        int r = p * 32 + orow;      // local out row (= in col)
        ushort8 o;
#pragma unroll
        for (int i = 0; i < 8; i++) o[i] = f2bf(t[ocb + i][r]);
        *(ushort8*)&out[(size_t)(c0 + r) * M + r0 + ocb] = o;
    }
}

// ---------------- grouped GEMM: 256x256 tile, BK=64, 8 waves, counted-vmcnt dbuf ----
// C[m,n] = sum_k A[m,k] * B[n,k]   (B pre-transposed, k contiguous)
// GATHER=1: A row m of expert e is xg[tok[e*CAP+m]]     (GEMM1)
// GATHER=0: A row m of expert e is G[base[e]+m]         (GEMM2)
// EPI=0: gelu -> bf16 G[(base+m)*N + n]
// EPI=1: atomicAdd(out[tok*N + n], wt * val)            (split-K safe)
//
// Structure (T-stack): 2x double-buffered 256x64 A/B tiles in LDS (128 KiB, 1 blk/CU),
//   staged by global_load_lds with PRE-SWIZZLED global source (chunk c -> c^(row&7)),
//   read back with the same XOR -> conflict-free ds_read_b128 (T2, rule #21).
//   Next tile staged before a counted `s_waitcnt vmcnt(8)` + raw s_barrier (T4) —
//   prefetch loads stay in flight across the barrier, never drained in main loop.
//   setprio(1) around each 32-MFMA cluster (T5). Bijective XCD chunking (T1):
//   mt fastest -> 16 consecutive blocks share one B panel per XCD.
template <int GATHER, int EPI, int NT, int KSPLIT>
__global__ __launch_bounds__(512, 2)
void gemm256_kernel(const unsigned short* __restrict__ Asrc,
                    const unsigned short* __restrict__ Bt,
                    int K, int N,
                    const int* __restrict__ cnt, const int* __restrict__ base,
                    const int* __restrict__ tok, const float* __restrict__ wt,
                    unsigned short* __restrict__ Gout, float* __restrict__ out) {
    const int nwg = E_EXP * MT256 * NT * KSPLIT;   // grid size, multiple of 8
    int bid = blockIdx.x;
    int swz = (bid & 7) * (nwg >> 3) + (bid >> 3); // XCD-chunked bijective remap
    const int mt = swz & (MT256 - 1);
    int rest = swz >> 4;                           // MT256 == 16
    const int ks = rest % KSPLIT; rest /= KSPLIT;
    const int nt = rest % NT;
    const int e  = rest / NT;

    const int cnt_e = cnt[e];
    const int m0 = mt * 256;
    if (m0 >= cnt_e) return;                       // before any barrier
    const int base_e = base[e];
    const int n0 = nt * 256;
    const int Kp = K / KSPLIT;
    const int kbegin = ks * Kp;
    const int KT = Kp >> 6;                        // K-tiles of 64

    const int tid = threadIdx.x;
    const int lane = tid & 63;
    const int wave = tid >> 6;
    const int l16 = lane & 15, quad = lane >> 4;
    const int wmg = wave >> 2;                     // 2 m-groups of 128 rows
    const int wng = wave & 3;                      // 4 n-groups of 64 cols

    // [buf][half][row][k] ; 64 KiB each -> 128 KiB total, 1 block/CU
    __shared__ unsigned short As[2][2][128][64];
    __shared__ unsigned short Bs[2][2][128][64];

    // ---- staging source pointers (8 gld16 per thread per K-tile) ----
    const int rsel = tid >> 3, csel = tid & 7;
    const int swzc = (csel ^ (rsel & 7)) * 8;      // pre-swizzled k-chunk (elements)
    const unsigned short* arow[4];
    const unsigned short* brow[4];
#pragma unroll
    for (int ii = 0; ii < 4; ii++) {
        int gr = m0 + ii * 64 + rsel;
        if (gr > cnt_e - 1) gr = cnt_e - 1;        // tail clamp (epilogue guards)
        const unsigned short* ab;
        if (GATHER) ab = Asrc + (size_t)tok[e * CAP + gr] * K;
        else        ab = Asrc + (size_t)(base_e + gr) * K;
        arow[ii] = ab + kbegin + swzc;
        brow[ii] = Bt + (size_t)e * N * K + (size_t)(n0 + ii * 64 + rsel) * K + kbegin + swzc;
    }
    unsigned short* alds = &As[0][0][0][0];
    unsigned short* blds = &Bs[0][0][0][0];
    const int dstoff = tid * 8;                    // shorts; linear DMA dest
    const int BUFS = 2 * 128 * 64;                 // shorts per buffer

    auto stage = [&](int b, int koff) {
#pragma unroll
        for (int ii = 0; ii < 4; ii++)
            gld16(arow[ii] + koff, alds + b * BUFS + ii * 4096 + dstoff);
#pragma unroll
        for (int ii = 0; ii < 4; ii++)
            gld16(brow[ii] + koff, blds + b * BUFS + ii * 4096 + dstoff);
    };

    f32x4 acc[8][4];
#pragma unroll
    for (int i = 0; i < 8; i++)
#pragma unroll
        for (int j = 0; j < 4; j++) acc[i][j] = (f32x4){0.f, 0.f, 0.f, 0.f};

    // read-side swizzled k offsets (elements): chunk q = ksub*4+quad, q ^= (row&7)=l16&7
    const int kx0 = ((quad    ) ^ (l16 & 7)) * 8;
    const int kx1 = ((quad + 4) ^ (l16 & 7)) * 8;

    stage(0, 0);
    int koff = 64;
    for (int t = 0; t < KT; ++t) {
        const int cur = t & 1;
        if (t + 1 < KT) {
            stage(cur ^ 1, koff);                  // 8 loads into the other buffer
            // wait only the PREVIOUS tile's 8 loads; the 8 just issued stay in flight
            asm volatile("s_waitcnt vmcnt(8)\n\ts_barrier" ::: "memory");
        } else {
            asm volatile("s_waitcnt vmcnt(0)\n\ts_barrier" ::: "memory");
        }

        short8 bfr[2][4];                          // all B frags resident (no re-read)
#pragma unroll
        for (int j = 0; j < 4; j++) {
            bfr[0][j] = *(const short8*)&Bs[cur][wng >> 1][(wng & 1) * 64 + j * 16 + l16][kx0];
            bfr[1][j] = *(const short8*)&Bs[cur][wng >> 1][(wng & 1) * 64 + j * 16 + l16][kx1];
        }
#pragma unroll
        for (int ms = 0; ms < 2; ms++) {
            short8 afr[2][4];
#pragma unroll
            for (int i = 0; i < 4; i++) {
                afr[0][i] = *(const short8*)&As[cur][wmg][(ms * 4 + i) * 16 + l16][kx0];
                afr[1][i] = *(const short8*)&As[cur][wmg][(ms * 4 + i) * 16 + l16][kx1];
            }
            __builtin_amdgcn_s_setprio(1);
#pragma unroll
            for (int i = 0; i < 4; i++)
#pragma unroll
                for (int j = 0; j < 4; j++) {
                    acc[ms * 4 + i][j] = __builtin_amdgcn_mfma_f32_16x16x32_bf16(
                        afr[0][i], bfr[0][j], acc[ms * 4 + i][j], 0, 0, 0);
                    acc[ms * 4 + i][j] = __builtin_amdgcn_mfma_f32_16x16x32_bf16(
                        afr[1][i], bfr[1][j], acc[ms * 4 + i][j], 0, 0, 0);
                }
            __builtin_amdgcn_s_setprio(0);
        }
        // all LDS reads retired (MFMA operand waits) -> next stage may overwrite
        asm volatile("s_barrier" ::: "memory");
        koff += 64;
    }

    // epilogue: D row = quad*4 + reg, D col = l16 (within each 16x16 tile)
    if (EPI == 0) {
#pragma unroll
        for (int i = 0; i < 8; i++) {
            int lm = wmg * 128 + i * 16 + quad * 4;
#pragma unroll
            for (int r = 0; r < 4; r++) {
                int gr = m0 + lm + r;
                if (gr < cnt_e) {
                    size_t rowoff = (size_t)(base_e + gr) * N;
#pragma unroll
                    for (int j = 0; j < 4; j++) {
                        int ncol = n0 + wng * 64 + j * 16 + l16;
                        Gout[rowoff + ncol] = f2bf(gelu_tanh(acc[i][j][r]));
                    }
                }
            }
        }
    } else {
#pragma unroll
        for (int i = 0; i < 8; i++) {
            int lm = wmg * 128 + i * 16 + quad * 4;
#pragma unroll
            for (int r = 0; r < 4; r++) {
                int gr = m0 + lm + r;
                if (gr < cnt_e) {
                    int tk = tok[e * CAP + gr];
                    float w = wt[e * CAP + gr];
                    float* orow = out + (size_t)tk * N;
#pragma unroll
                    for (int j = 0; j < 4; j++) {
                        int ncol = n0 + wng * 64 + j * 16 + l16;
                        atomicAdd(&orow[ncol], w * acc[i][j][r]);
                    }
                }
            }
        }
    }
}

extern "C" void kernel_launch(void* const* d_in, const int* in_sizes, int n_in,
                              void* d_out, int out_size, void* d_ws, size_t ws_size,
                              hipStream_t stream) {
    const float* x      = (const float*)d_in[0];
    const float* logits = (const float*)d_in[1];
    const float* w1     = (const float*)d_in[2];
    const float* w2     = (const float*)d_in[3];
    float* out = (float*)d_out;
    char* ws = (char*)d_ws;

    // workspace layout
    const size_t OFF_CNT  = 0;
    const size_t OFF_BASE = 64;
    const size_t OFF_TOK  = 1024;
    const size_t OFF_WT   = OFF_TOK + (size_t)E_EXP * CAP * 4;
    const size_t OFF_XG   = 1u << 20;
    const size_t OFF_W1T  = OFF_XG + (size_t)T_TOKENS * H_DIM * 2;
    const size_t OFF_W2T  = OFF_W1T + (size_t)E_EXP * H_DIM * F_DIM * 2;
    const size_t OFF_G    = OFF_W2T + (size_t)E_EXP * H_DIM * F_DIM * 2;

    int* cnt  = (int*)(ws + OFF_CNT);
    int* base = (int*)(ws + OFF_BASE);
    int* tok  = (int*)(ws + OFF_TOK);
    float* wt = (float*)(ws + OFF_WT);
    unsigned short* xg  = (unsigned short*)(ws + OFF_XG);
    unsigned short* w1t = (unsigned short*)(ws + OFF_W1T);
    unsigned short* w2t = (unsigned short*)(ws + OFF_W2T);
    unsigned short* G   = (unsigned short*)(ws + OFF_G);

    hipMemsetAsync(d_out, 0, (size_t)out_size * sizeof(float), stream);
    hipMemsetAsync(cnt, 0, 64, stream);

    router_kernel<<<T_TOKENS / 256, 256, 0, stream>>>(logits, cnt, tok, wt);
    base_kernel<<<1, 64, 0, stream>>>(cnt, base);
    cvtx_kernel<<<(T_TOKENS * H_DIM / 4) / 256, 256, 0, stream>>>(x, xg);
    // w1 [E,H,F] -> w1t [E,F,H]
    tcvt_kernel<<<dim3(H_DIM / 64, F_DIM / 64, E_EXP), 256, 0, stream>>>(w1, w1t, H_DIM, F_DIM);
    // w2 [E,F,H] -> w2t [E,H,F]
    tcvt_kernel<<<dim3(F_DIM / 64, H_DIM / 64, E_EXP), 256, 0, stream>>>(w2, w2t, F_DIM, H_DIM);
    // GEMM1: 256x256 tiles, NT=16 (F=4096), no K-split. grid = 8e*16mt*16nt = 2048
    gemm256_kernel<1, 0, 16, 1><<<E_EXP * MT256 * 16 * 1, 512, 0, stream>>>(
        xg, w1t, H_DIM, F_DIM, cnt, base, tok, wt, G, nullptr);
    // GEMM2: 256x256 tiles, NT=4 (H=1024), split-K=2 (epilogue already atomic).
    // grid = 8e*16mt*4nt*2ks = 1024
    gemm256_kernel<0, 1, 4, 2><<<E_EXP * MT256 * 4 * 2, 512, 0, stream>>>(
        G, w2t, F_DIM, H_DIM, cnt, base, tok, wt, nullptr, out);
    (void)in_sizes; (void)n_in; (void)ws_size;
}